// Round 7
// baseline (453.073 us; speedup 1.0000x reference)
//
#include <hip/hip_runtime.h>

#define SEQ   2048
#define NHEAD 16
#define DKK   64
#define HID   1024

typedef __attribute__((ext_vector_type(8))) short bf16x8;
typedef __attribute__((ext_vector_type(4))) float f32x4;

__device__ __forceinline__ unsigned short f32_bf16(float f) {
    unsigned int u = __builtin_bit_cast(unsigned int, f);
    u += 0x7fffu + ((u >> 16) & 1u);
    return (unsigned short)(u >> 16);
}

__device__ __forceinline__ unsigned int pack_bf16x2(float a, float b) {
    return (unsigned int)f32_bf16(a) | ((unsigned int)f32_bf16(b) << 16);
}

// async global->LDS 16B copy (DMA, no VGPR round-trip)
__device__ __forceinline__ void glds16(const void* g, void* l) {
    __builtin_amdgcn_global_load_lds(
        (const __attribute__((address_space(1))) unsigned int*)g,
        (__attribute__((address_space(3))) unsigned int*)l, 16, 0, 0);
}

// ---------------------------------------------------------------------------
// Kernel 0: fused prepass — fp32->bf16 of q,k,v,Wq,Wk,Wv,Wo + mask bit-pack,
// one launch (region-split grid).  NX=2^20 uint2-chunks per x buf, NW=2^18
// per W buf, NM=2^17 mask words.
// ---------------------------------------------------------------------------
__global__ __launch_bounds__(256)
void prepass_kernel(const float* __restrict__ q, const float* __restrict__ k,
                    const float* __restrict__ v,
                    const float* __restrict__ Wq, const float* __restrict__ Wk,
                    const float* __restrict__ Wv, const float* __restrict__ Wo,
                    const int* __restrict__ mask,
                    unsigned short* __restrict__ qb, unsigned short* __restrict__ kb,
                    unsigned short* __restrict__ vb,
                    unsigned short* __restrict__ Wqb, unsigned short* __restrict__ Wkb,
                    unsigned short* __restrict__ Wvb, unsigned short* __restrict__ Wob,
                    unsigned long long* __restrict__ Mb)
{
    const int NX = 1 << 20, NW = 1 << 18;
    int idx = blockIdx.x * 256 + threadIdx.x;
    if (idx < 3 * NX) {
        int r = idx >> 20, i = idx & (NX - 1);
        const float* s = (r == 0) ? q : (r == 1) ? k : v;
        unsigned short* d = (r == 0) ? qb : (r == 1) ? kb : vb;
        float4 a = ((const float4*)s)[i];
        ((uint2*)d)[i] = make_uint2(pack_bf16x2(a.x, a.y), pack_bf16x2(a.z, a.w));
    } else if (idx < 3 * NX + 4 * NW) {
        int wi = idx - 3 * NX;
        int r = wi >> 18, i = wi & (NW - 1);
        const float* s = (r == 0) ? Wq : (r == 1) ? Wk : (r == 2) ? Wv : Wo;
        unsigned short* d = (r == 0) ? Wqb : (r == 1) ? Wkb : (r == 2) ? Wvb : Wob;
        float4 a = ((const float4*)s)[i];
        ((uint2*)d)[i] = make_uint2(pack_bf16x2(a.x, a.y), pack_bf16x2(a.z, a.w));
    } else {
        int m = idx - (3 * NX + 4 * NW);
        const int* src = mask + (size_t)m * 64;
        unsigned long long w = 0;
        #pragma unroll
        for (int i = 0; i < 16; ++i) {
            int4 m4 = *(const int4*)(src + i * 4);
            w |= (unsigned long long)(m4.x != 0) << (i * 4 + 0);
            w |= (unsigned long long)(m4.y != 0) << (i * 4 + 1);
            w |= (unsigned long long)(m4.z != 0) << (i * 4 + 2);
            w |= (unsigned long long)(m4.w != 0) << (i * 4 + 3);
        }
        Mb[m] = w;
    }
}

// ---------------------------------------------------------------------------
// Kernel 1: QKV projections, m97-structure (global_load_lds width-16, BK=32,
// XOR swizzle).  Epilogue scatters to Qh/Kh=[b,h,s,d], Vt=[b,h,d,s].
// ---------------------------------------------------------------------------
__global__ __launch_bounds__(256, 2)
void proj_kernel(const unsigned short* __restrict__ xq, const unsigned short* __restrict__ xk,
                 const unsigned short* __restrict__ xv,
                 const unsigned short* __restrict__ Wqb, const unsigned short* __restrict__ Wkb,
                 const unsigned short* __restrict__ Wvb,
                 const float* __restrict__ bq_, const float* __restrict__ bk_,
                 const float* __restrict__ bv_,
                 unsigned short* __restrict__ Qh, unsigned short* __restrict__ Kh,
                 unsigned short* __restrict__ Vt)
{
    const int z = blockIdx.z;
    const unsigned short* X; const unsigned short* W; const float* bias;
    if (z == 0)      { X = xq; W = Wqb; bias = bq_; }
    else if (z == 1) { X = xk; W = Wkb; bias = bk_; }
    else             { X = xv; W = Wvb; bias = bv_; }

    const int m0 = blockIdx.x * 128;
    const int n0 = blockIdx.y * 128;
    const int tid  = threadIdx.x;
    const int lane = tid & 63, wid = tid >> 6;
    const int wm = (wid >> 1) * 64, wn = (wid & 1) * 64;
    const int l15 = lane & 15, quad = lane >> 4;

    __shared__ __align__(16) unsigned short As[128 * 32];
    __shared__ __align__(16) unsigned short Bs[128 * 32];

    const int r0 = tid >> 2, cg = tid & 3;
    const unsigned short* gA = X + (size_t)(m0 + r0) * HID + ((cg ^ (r0 & 3)) * 8);
    const unsigned short* gB = W + (size_t)(n0 + r0) * HID + ((cg ^ (r0 & 3)) * 8);
    unsigned short* lA0 = &As[tid * 8];
    unsigned short* lA1 = &As[(tid + 256) * 8];
    unsigned short* lB0 = &Bs[tid * 8];
    unsigned short* lB1 = &Bs[(tid + 256) * 8];
    const int cgsel = (quad ^ (l15 & 3)) * 8;

    f32x4 acc[4][4];
    #pragma unroll
    for (int i = 0; i < 4; ++i)
        #pragma unroll
        for (int j = 0; j < 4; ++j)
            acc[i][j] = f32x4{0.f, 0.f, 0.f, 0.f};

    for (int k0 = 0; k0 < HID; k0 += 32) {
        glds16(gA + k0, lA0);
        glds16(gA + (size_t)64 * HID + k0, lA1);
        glds16(gB + k0, lB0);
        glds16(gB + (size_t)64 * HID + k0, lB1);
        __syncthreads();

        bf16x8 af[4], bfr[4];
        #pragma unroll
        for (int mi = 0; mi < 4; ++mi)
            af[mi] = *(const bf16x8*)&As[(wm + mi * 16 + l15) * 32 + cgsel];
        #pragma unroll
        for (int ni = 0; ni < 4; ++ni)
            bfr[ni] = *(const bf16x8*)&Bs[(wn + ni * 16 + l15) * 32 + cgsel];
        #pragma unroll
        for (int mi = 0; mi < 4; ++mi)
            #pragma unroll
            for (int ni = 0; ni < 4; ++ni)
                acc[mi][ni] = __builtin_amdgcn_mfma_f32_16x16x32_bf16(
                    af[mi], bfr[ni], acc[mi][ni], 0, 0, 0);
        __syncthreads();
    }

    #pragma unroll
    for (int mi = 0; mi < 4; ++mi) {
        #pragma unroll
        for (int ni = 0; ni < 4; ++ni) {
            int n = n0 + wn + ni * 16 + l15;
            float bv = bias[n];
            int hh = n >> 6, d = n & 63;
            #pragma unroll
            for (int r = 0; r < 4; ++r) {
                int m = m0 + wm + mi * 16 + quad * 4 + r;
                int bb = m >> 11, s = m & 2047;
                unsigned short hv = f32_bf16(acc[mi][ni][r] + bv);
                if (z == 0)
                    Qh[((size_t)(bb * NHEAD + hh) * SEQ + s) * DKK + d] = hv;
                else if (z == 1)
                    Kh[((size_t)(bb * NHEAD + hh) * SEQ + s) * DKK + d] = hv;
                else
                    Vt[((size_t)(bb * NHEAD + hh) * DKK + d) * SEQ + s] = hv;
            }
        }
    }
}

// ---------------------------------------------------------------------------
// Kernel 2: split-K flash attention.  Q-tile staged in LDS (shared by all 4
// waves — frees 32 held VGPRs -> 3 waves/SIMD).  Wave w handles k-tiles
// [8w,8w+8); K/V/mask direct from global; no block barriers in k-loop.
// p = maskbit ? exp2(s*C) : 1.0 (reference masks logits to 1e-9, max=0 safe).
// Row sums via ones-MFMA; merge = plain sum of (O,l) partials.
// ---------------------------------------------------------------------------
__global__ __launch_bounds__(256, 3)
void attn_kernel(const unsigned short* __restrict__ Qh, const unsigned short* __restrict__ Kh,
                 const unsigned short* __restrict__ Vt,
                 const unsigned long long* __restrict__ Mb,
                 unsigned short* __restrict__ Om)
{
    const int qt = blockIdx.x;       // 0..31 (q-tile of 64)
    const int h  = blockIdx.y;
    const int b  = blockIdx.z;
    const int tid  = threadIdx.x;
    const int lane = tid & 63, wid = tid >> 6;
    const int l15 = lane & 15, quad = lane >> 4;
    const int q0 = qt * 64;

    const size_t hoff = (size_t)(b * NHEAD + h) * SEQ * DKK;
    const unsigned short* Qp = Qh + hoff;
    const unsigned short* Kp = Kh + hoff;
    const unsigned short* Vp = Vt + hoff;   // [d][s]

    __shared__ __align__(16) unsigned short Qs[64 * 72];     // shared Q tile
    __shared__ __align__(16) unsigned short Ps[4][64 * 72];  // per-wave P buffer
    __shared__ float lbuf[4][64];
    float* obuf = (float*)&Ps[0][0];        // 64x66 f32 merge buffer (aliased)

    // cooperative Q stage (coalesced uint4)
    #pragma unroll
    for (int p = 0; p < 2; ++p) {
        int c = tid + p * 256;
        int row = c >> 3, c8 = c & 7;
        *(uint4*)&Qs[row * 72 + c8 * 8] = *(const uint4*)(Qp + (size_t)(q0 + row) * DKK + c8 * 8);
    }
    __syncthreads();

    bf16x8 onesf;
    #pragma unroll
    for (int i = 0; i < 8; ++i) onesf[i] = (short)0x3F80;

    f32x4 o_acc[4][4];
    f32x4 l_acc[4];
    #pragma unroll
    for (int mi = 0; mi < 4; ++mi) {
        #pragma unroll
        for (int nd = 0; nd < 4; ++nd) o_acc[mi][nd] = f32x4{0.f, 0.f, 0.f, 0.f};
        l_acc[mi] = f32x4{0.f, 0.f, 0.f, 0.f};
    }

    const float C = 0.125f * 1.44269504f;   // 1/sqrt(dk) * log2(e)

    const unsigned long long* Mrow = Mb + ((size_t)b * SEQ + q0 + quad * 4) * (SEQ / 64);

    const int ktBeg = wid * 8, ktEnd = ktBeg + 8;
    for (int kt = ktBeg; kt < ktEnd; ++kt) {
        const int kbase = kt * 64;
        bf16x8 kb[2][4], vb[2][4];
        #pragma unroll
        for (int kc = 0; kc < 2; ++kc)
            #pragma unroll
            for (int ni = 0; ni < 4; ++ni) {
                kb[kc][ni] = *(const bf16x8*)(Kp + (size_t)(kbase + ni * 16 + l15) * DKK
                                              + kc * 32 + quad * 8);
                vb[kc][ni] = *(const bf16x8*)(Vp + (size_t)(ni * 16 + l15) * SEQ
                                              + kbase + kc * 32 + quad * 8);
            }

        #pragma unroll
        for (int mi = 0; mi < 4; ++mi) {
            unsigned long long mw[4];
            #pragma unroll
            for (int r = 0; r < 4; ++r)
                mw[r] = Mrow[(size_t)(mi * 16 + r) * (SEQ / 64) + kt] >> l15;

            f32x4 s[4];
            #pragma unroll
            for (int ni = 0; ni < 4; ++ni) s[ni] = f32x4{0.f, 0.f, 0.f, 0.f};
            #pragma unroll
            for (int kc = 0; kc < 2; ++kc) {
                bf16x8 qa = *(const bf16x8*)&Qs[(mi * 16 + l15) * 72 + kc * 32 + quad * 8];
                #pragma unroll
                for (int ni = 0; ni < 4; ++ni)
                    s[ni] = __builtin_amdgcn_mfma_f32_16x16x32_bf16(
                        qa, kb[kc][ni], s[ni], 0, 0, 0);
            }

            #pragma unroll
            for (int r = 0; r < 4; ++r) {
                unsigned short* prow = &Ps[wid][(mi * 16 + quad * 4 + r) * 72];
                #pragma unroll
                for (int ni = 0; ni < 4; ++ni) {
                    float e = exp2f(s[ni][r] * C);
                    float p = (mw[r] >> (ni * 16)) & 1 ? e : 1.0f;
                    prow[ni * 16 + l15] = f32_bf16(p);
                }
            }

            #pragma unroll
            for (int kc = 0; kc < 2; ++kc) {
                bf16x8 pa = *(const bf16x8*)&Ps[wid][(mi * 16 + l15) * 72 + kc * 32 + quad * 8];
                l_acc[mi] = __builtin_amdgcn_mfma_f32_16x16x32_bf16(
                    pa, onesf, l_acc[mi], 0, 0, 0);
                #pragma unroll
                for (int nd = 0; nd < 4; ++nd)
                    o_acc[mi][nd] = __builtin_amdgcn_mfma_f32_16x16x32_bf16(
                        pa, vb[kc][nd], o_acc[mi][nd], 0, 0, 0);
            }
        }
    }

    // ---- merge 4 per-wave partial (O, l) by plain summation ----
    if (l15 == 0) {
        #pragma unroll
        for (int mi = 0; mi < 4; ++mi)
            #pragma unroll
            for (int r = 0; r < 4; ++r)
                lbuf[wid][mi * 16 + quad * 4 + r] = l_acc[mi][r];
    }
    __syncthreads();

    if (wid == 0) {
        #pragma unroll
        for (int mi = 0; mi < 4; ++mi)
            #pragma unroll
            for (int nd = 0; nd < 4; ++nd)
                #pragma unroll
                for (int r = 0; r < 4; ++r)
                    obuf[(mi * 16 + quad * 4 + r) * 66 + nd * 16 + l15] = o_acc[mi][nd][r];
    }
    __syncthreads();
    if (wid == 1) {
        #pragma unroll
        for (int mi = 0; mi < 4; ++mi)
            #pragma unroll
            for (int nd = 0; nd < 4; ++nd)
                #pragma unroll
                for (int r = 0; r < 4; ++r)
                    obuf[(mi * 16 + quad * 4 + r) * 66 + nd * 16 + l15] += o_acc[mi][nd][r];
    }
    __syncthreads();
    if (wid == 2) {
        #pragma unroll
        for (int mi = 0; mi < 4; ++mi)
            #pragma unroll
            for (int nd = 0; nd < 4; ++nd)
                #pragma unroll
                for (int r = 0; r < 4; ++r)
                    obuf[(mi * 16 + quad * 4 + r) * 66 + nd * 16 + l15] += o_acc[mi][nd][r];
    }
    __syncthreads();
    if (wid == 3) {
        #pragma unroll
        for (int mi = 0; mi < 4; ++mi) {
            #pragma unroll
            for (int r = 0; r < 4; ++r) {
                int row = mi * 16 + quad * 4 + r;
                float L = lbuf[0][row] + lbuf[1][row] + lbuf[2][row] + lbuf[3][row];
                float rinv = 1.0f / L;
                #pragma unroll
                for (int nd = 0; nd < 4; ++nd) {
                    float tot = obuf[row * 66 + nd * 16 + l15] + o_acc[mi][nd][r];
                    Om[((size_t)b * SEQ + q0 + row) * HID + h * DKK + nd * 16 + l15] =
                        f32_bf16(tot * rinv);
                }
            }
        }
    }
}

// ---------------------------------------------------------------------------
// Kernel 3: out = Om @ Wo^T + bo (fp32 out), m97-structure like proj.
// ---------------------------------------------------------------------------
__global__ __launch_bounds__(256, 2)
void outproj_kernel(const unsigned short* __restrict__ Om, const unsigned short* __restrict__ Wob,
                    const float* __restrict__ bo_, float* __restrict__ out)
{
    const int m0 = blockIdx.x * 128;
    const int n0 = blockIdx.y * 128;
    const int tid  = threadIdx.x;
    const int lane = tid & 63, wid = tid >> 6;
    const int wm = (wid >> 1) * 64, wn = (wid & 1) * 64;
    const int l15 = lane & 15, quad = lane >> 4;

    __shared__ __align__(16) unsigned short As[128 * 32];
    __shared__ __align__(16) unsigned short Bs[128 * 32];

    const int r0 = tid >> 2, cg = tid & 3;
    const unsigned short* gA = Om + (size_t)(m0 + r0) * HID + ((cg ^ (r0 & 3)) * 8);
    const unsigned short* gB = Wob + (size_t)(n0 + r0) * HID + ((cg ^ (r0 & 3)) * 8);
    unsigned short* lA0 = &As[tid * 8];
    unsigned short* lA1 = &As[(tid + 256) * 8];
    unsigned short* lB0 = &Bs[tid * 8];
    unsigned short* lB1 = &Bs[(tid + 256) * 8];
    const int cgsel = (quad ^ (l15 & 3)) * 8;

    f32x4 acc[4][4];
    #pragma unroll
    for (int i = 0; i < 4; ++i)
        #pragma unroll
        for (int j = 0; j < 4; ++j)
            acc[i][j] = f32x4{0.f, 0.f, 0.f, 0.f};

    for (int k0 = 0; k0 < HID; k0 += 32) {
        glds16(gA + k0, lA0);
        glds16(gA + (size_t)64 * HID + k0, lA1);
        glds16(gB + k0, lB0);
        glds16(gB + (size_t)64 * HID + k0, lB1);
        __syncthreads();

        bf16x8 af[4], bfr[4];
        #pragma unroll
        for (int mi = 0; mi < 4; ++mi)
            af[mi] = *(const bf16x8*)&As[(wm + mi * 16 + l15) * 32 + cgsel];
        #pragma unroll
        for (int ni = 0; ni < 4; ++ni)
            bfr[ni] = *(const bf16x8*)&Bs[(wn + ni * 16 + l15) * 32 + cgsel];
        #pragma unroll
        for (int mi = 0; mi < 4; ++mi)
            #pragma unroll
            for (int ni = 0; ni < 4; ++ni)
                acc[mi][ni] = __builtin_amdgcn_mfma_f32_16x16x32_bf16(
                    af[mi], bfr[ni], acc[mi][ni], 0, 0, 0);
        __syncthreads();
    }

    #pragma unroll
    for (int mi = 0; mi < 4; ++mi) {
        #pragma unroll
        for (int ni = 0; ni < 4; ++ni) {
            int n = n0 + wn + ni * 16 + l15;
            float bv = bo_[n];
            #pragma unroll
            for (int r = 0; r < 4; ++r) {
                int m = m0 + wm + mi * 16 + quad * 4 + r;
                out[(size_t)m * HID + n] = acc[mi][ni][r] + bv;
            }
        }
    }
}

// ---------------------------------------------------------------------------
extern "C" void kernel_launch(void* const* d_in, const int* in_sizes, int n_in,
                              void* d_out, int out_size, void* d_ws, size_t ws_size,
                              hipStream_t stream) {
    const float* q    = (const float*)d_in[0];
    const float* k    = (const float*)d_in[1];
    const float* v    = (const float*)d_in[2];
    const int*   mask = (const int*)  d_in[3];
    const float* Wq   = (const float*)d_in[4];
    const float* bq   = (const float*)d_in[5];
    const float* Wk   = (const float*)d_in[6];
    const float* bk   = (const float*)d_in[7];
    const float* Wv   = (const float*)d_in[8];
    const float* bv   = (const float*)d_in[9];
    const float* Wo   = (const float*)d_in[10];
    const float* bo   = (const float*)d_in[11];
    float* out = (float*)d_out;

    // workspace layout (bf16 element offsets):
    unsigned short* ws  = (unsigned short*)d_ws;
    unsigned short* qb  = ws;                  // 4194304 elems (B*S*H)
    unsigned short* kbx = ws + 4194304;
    unsigned short* vbx = ws + 8388608;
    unsigned short* Wqb = ws + 12582912;       // 1048576 elems each
    unsigned short* Wkb = ws + 13631488;
    unsigned short* Wvb = ws + 14680064;
    unsigned short* Wob = ws + 15728640;
    unsigned short* Qh  = ws + 16777216;
    unsigned short* Kh  = ws + 20971520;
    unsigned short* Vt  = ws + 25165824;
    unsigned short* Om  = ws;                  // alias qb (dead after proj)
    unsigned long long* Mb = (unsigned long long*)(ws + 29360128);  // 1 MB

    // prepass work items: 3*2^20 (x cvt) + 4*2^18 (W cvt) + 2^17 (mask)
    const int nPre = 3 * (1 << 20) + 4 * (1 << 18) + (1 << 17);
    prepass_kernel<<<dim3(nPre / 256), 256, 0, stream>>>(
        q, k, v, Wq, Wk, Wv, Wo, mask, qb, kbx, vbx, Wqb, Wkb, Wvb, Wob, Mb);

    proj_kernel<<<dim3(32, 8, 3), 256, 0, stream>>>(qb, kbx, vbx, Wqb, Wkb, Wvb,
                                                    bq, bk, bv, Qh, Kh, Vt);
    attn_kernel<<<dim3(32, NHEAD, 2), 256, 0, stream>>>(Qh, Kh, Vt, Mb, Om);
    outproj_kernel<<<dim3(32, 8, 1), 256, 0, stream>>>(Om, Wob, bo, out);
}

// Round 8
// 373.667 us; speedup vs baseline: 1.2125x; 1.2125x over previous
//
#include <hip/hip_runtime.h>

#define SEQ   2048
#define NHEAD 16
#define DKK   64
#define HID   1024

typedef __attribute__((ext_vector_type(8))) short bf16x8;
typedef __attribute__((ext_vector_type(4))) float f32x4;

__device__ __forceinline__ unsigned short f32_bf16(float f) {
    unsigned int u = __builtin_bit_cast(unsigned int, f);
    u += 0x7fffu + ((u >> 16) & 1u);
    return (unsigned short)(u >> 16);
}

__device__ __forceinline__ unsigned int pack_bf16x2(float a, float b) {
    return (unsigned int)f32_bf16(a) | ((unsigned int)f32_bf16(b) << 16);
}

// async global->LDS 16B copy (DMA, no VGPR round-trip)
__device__ __forceinline__ void glds16(const void* g, void* l) {
    __builtin_amdgcn_global_load_lds(
        (const __attribute__((address_space(1))) unsigned int*)g,
        (__attribute__((address_space(3))) unsigned int*)l, 16, 0, 0);
}

// ---------------------------------------------------------------------------
// Kernel 0: fused prepass — fp32->bf16 of q,k,v,Wq,Wk,Wv,Wo + mask bit-pack,
// one launch (region-split grid).
// ---------------------------------------------------------------------------
__global__ __launch_bounds__(256)
void prepass_kernel(const float* __restrict__ q, const float* __restrict__ k,
                    const float* __restrict__ v,
                    const float* __restrict__ Wq, const float* __restrict__ Wk,
                    const float* __restrict__ Wv, const float* __restrict__ Wo,
                    const int* __restrict__ mask,
                    unsigned short* __restrict__ qb, unsigned short* __restrict__ kb,
                    unsigned short* __restrict__ vb,
                    unsigned short* __restrict__ Wqb, unsigned short* __restrict__ Wkb,
                    unsigned short* __restrict__ Wvb, unsigned short* __restrict__ Wob,
                    unsigned long long* __restrict__ Mb)
{
    const int NX = 1 << 20, NW = 1 << 18;
    int idx = blockIdx.x * 256 + threadIdx.x;
    if (idx < 3 * NX) {
        int r = idx >> 20, i = idx & (NX - 1);
        const float* s = (r == 0) ? q : (r == 1) ? k : v;
        unsigned short* d = (r == 0) ? qb : (r == 1) ? kb : vb;
        float4 a = ((const float4*)s)[i];
        ((uint2*)d)[i] = make_uint2(pack_bf16x2(a.x, a.y), pack_bf16x2(a.z, a.w));
    } else if (idx < 3 * NX + 4 * NW) {
        int wi = idx - 3 * NX;
        int r = wi >> 18, i = wi & (NW - 1);
        const float* s = (r == 0) ? Wq : (r == 1) ? Wk : (r == 2) ? Wv : Wo;
        unsigned short* d = (r == 0) ? Wqb : (r == 1) ? Wkb : (r == 2) ? Wvb : Wob;
        float4 a = ((const float4*)s)[i];
        ((uint2*)d)[i] = make_uint2(pack_bf16x2(a.x, a.y), pack_bf16x2(a.z, a.w));
    } else {
        int m = idx - (3 * NX + 4 * NW);
        const int* src = mask + (size_t)m * 64;
        unsigned long long w = 0;
        #pragma unroll
        for (int i = 0; i < 16; ++i) {
            int4 m4 = *(const int4*)(src + i * 4);
            w |= (unsigned long long)(m4.x != 0) << (i * 4 + 0);
            w |= (unsigned long long)(m4.y != 0) << (i * 4 + 1);
            w |= (unsigned long long)(m4.z != 0) << (i * 4 + 2);
            w |= (unsigned long long)(m4.w != 0) << (i * 4 + 3);
        }
        Mb[m] = w;
    }
}

// ---------------------------------------------------------------------------
// Kernel 1: QKV projections, m97-structure (global_load_lds width-16, BK=32,
// XOR swizzle).  Epilogue scatters to Qh/Kh=[b,h,s,d]; Vt=[b,h,d,s] with the
// k-permutation sigma(s%64) = 4*(s&15) + ((s>>4)&3) applied inside each
// 64-block of s, matching attn's P storage order (MFMA k-order is free).
// ---------------------------------------------------------------------------
__global__ __launch_bounds__(256, 2)
void proj_kernel(const unsigned short* __restrict__ xq, const unsigned short* __restrict__ xk,
                 const unsigned short* __restrict__ xv,
                 const unsigned short* __restrict__ Wqb, const unsigned short* __restrict__ Wkb,
                 const unsigned short* __restrict__ Wvb,
                 const float* __restrict__ bq_, const float* __restrict__ bk_,
                 const float* __restrict__ bv_,
                 unsigned short* __restrict__ Qh, unsigned short* __restrict__ Kh,
                 unsigned short* __restrict__ Vt)
{
    const int z = blockIdx.z;
    const unsigned short* X; const unsigned short* W; const float* bias;
    if (z == 0)      { X = xq; W = Wqb; bias = bq_; }
    else if (z == 1) { X = xk; W = Wkb; bias = bk_; }
    else             { X = xv; W = Wvb; bias = bv_; }

    const int m0 = blockIdx.x * 128;
    const int n0 = blockIdx.y * 128;
    const int tid  = threadIdx.x;
    const int lane = tid & 63, wid = tid >> 6;
    const int wm = (wid >> 1) * 64, wn = (wid & 1) * 64;
    const int l15 = lane & 15, quad = lane >> 4;

    __shared__ __align__(16) unsigned short As[128 * 32];
    __shared__ __align__(16) unsigned short Bs[128 * 32];

    const int r0 = tid >> 2, cg = tid & 3;
    const unsigned short* gA = X + (size_t)(m0 + r0) * HID + ((cg ^ (r0 & 3)) * 8);
    const unsigned short* gB = W + (size_t)(n0 + r0) * HID + ((cg ^ (r0 & 3)) * 8);
    unsigned short* lA0 = &As[tid * 8];
    unsigned short* lA1 = &As[(tid + 256) * 8];
    unsigned short* lB0 = &Bs[tid * 8];
    unsigned short* lB1 = &Bs[(tid + 256) * 8];
    const int cgsel = (quad ^ (l15 & 3)) * 8;

    f32x4 acc[4][4];
    #pragma unroll
    for (int i = 0; i < 4; ++i)
        #pragma unroll
        for (int j = 0; j < 4; ++j)
            acc[i][j] = f32x4{0.f, 0.f, 0.f, 0.f};

    for (int k0 = 0; k0 < HID; k0 += 32) {
        glds16(gA + k0, lA0);
        glds16(gA + (size_t)64 * HID + k0, lA1);
        glds16(gB + k0, lB0);
        glds16(gB + (size_t)64 * HID + k0, lB1);
        __syncthreads();

        bf16x8 af[4], bfr[4];
        #pragma unroll
        for (int mi = 0; mi < 4; ++mi)
            af[mi] = *(const bf16x8*)&As[(wm + mi * 16 + l15) * 32 + cgsel];
        #pragma unroll
        for (int ni = 0; ni < 4; ++ni)
            bfr[ni] = *(const bf16x8*)&Bs[(wn + ni * 16 + l15) * 32 + cgsel];
        #pragma unroll
        for (int mi = 0; mi < 4; ++mi)
            #pragma unroll
            for (int ni = 0; ni < 4; ++ni)
                acc[mi][ni] = __builtin_amdgcn_mfma_f32_16x16x32_bf16(
                    af[mi], bfr[ni], acc[mi][ni], 0, 0, 0);
        __syncthreads();
    }

    #pragma unroll
    for (int mi = 0; mi < 4; ++mi) {
        #pragma unroll
        for (int ni = 0; ni < 4; ++ni) {
            int n = n0 + wn + ni * 16 + l15;
            float bv = bias[n];
            int hh = n >> 6, d = n & 63;
            #pragma unroll
            for (int r = 0; r < 4; ++r) {
                int m = m0 + wm + mi * 16 + quad * 4 + r;
                int bb = m >> 11, s = m & 2047;
                unsigned short hv = f32_bf16(acc[mi][ni][r] + bv);
                if (z == 0)
                    Qh[((size_t)(bb * NHEAD + hh) * SEQ + s) * DKK + d] = hv;
                else if (z == 1)
                    Kh[((size_t)(bb * NHEAD + hh) * SEQ + s) * DKK + d] = hv;
                else {
                    int sp = (s & ~63) | (4 * (s & 15) + ((s >> 4) & 3));  // sigma
                    Vt[((size_t)(bb * NHEAD + hh) * DKK + d) * SEQ + sp] = hv;
                }
            }
        }
    }
}

// ---------------------------------------------------------------------------
// Kernel 2: split-K flash attention (R6 structure: (256,2), Q in registers,
// no block barriers in k-loop).  P is stored in LDS in permuted k-order
// sigma(kcol) = 4*l15 + ni, so each lane writes ONE ds_write_b64 per row
// (4 packed bf16) instead of 16 scattered u16.  Vt was pre-permuted with the
// same sigma, so vb b128 loads line up; ones/l are permutation-invariant.
// p = maskbit ? exp2(s*C) : 1.0 (reference masks logits to 1e-9; max=0 safe).
// ---------------------------------------------------------------------------
__global__ __launch_bounds__(256, 2)
void attn_kernel(const unsigned short* __restrict__ Qh, const unsigned short* __restrict__ Kh,
                 const unsigned short* __restrict__ Vt,
                 const unsigned long long* __restrict__ Mb,
                 unsigned short* __restrict__ Om)
{
    const int qt = blockIdx.x;       // 0..31 (q-tile of 64)
    const int h  = blockIdx.y;
    const int b  = blockIdx.z;
    const int tid  = threadIdx.x;
    const int lane = tid & 63, wid = tid >> 6;
    const int l15 = lane & 15, quad = lane >> 4;
    const int q0 = qt * 64;

    const size_t hoff = (size_t)(b * NHEAD + h) * SEQ * DKK;
    const unsigned short* Qp = Qh + hoff;
    const unsigned short* Kp = Kh + hoff;
    const unsigned short* Vp = Vt + hoff;   // [d][s-permuted]

    __shared__ __align__(16) unsigned short Ps[4][64 * 72];
    __shared__ float lbuf[4][64];
    float* obuf = (float*)&Ps[0][0];

    bf16x8 qf[4][2];
    #pragma unroll
    for (int mi = 0; mi < 4; ++mi)
        #pragma unroll
        for (int kc = 0; kc < 2; ++kc)
            qf[mi][kc] = *(const bf16x8*)(Qp + (size_t)(q0 + mi * 16 + l15) * DKK
                                          + kc * 32 + quad * 8);

    bf16x8 onesf;
    #pragma unroll
    for (int i = 0; i < 8; ++i) onesf[i] = (short)0x3F80;

    f32x4 o_acc[4][4];
    f32x4 l_acc[4];
    #pragma unroll
    for (int mi = 0; mi < 4; ++mi) {
        #pragma unroll
        for (int nd = 0; nd < 4; ++nd) o_acc[mi][nd] = f32x4{0.f, 0.f, 0.f, 0.f};
        l_acc[mi] = f32x4{0.f, 0.f, 0.f, 0.f};
    }

    const float C = 0.125f * 1.44269504f;

    const unsigned long long* Mrow = Mb + ((size_t)b * SEQ + q0 + quad * 4) * (SEQ / 64);

    const int ktBeg = wid * 8, ktEnd = ktBeg + 8;
    for (int kt = ktBeg; kt < ktEnd; ++kt) {
        const int kbase = kt * 64;
        bf16x8 kb[2][4], vb[2][4];
        #pragma unroll
        for (int kc = 0; kc < 2; ++kc)
            #pragma unroll
            for (int ni = 0; ni < 4; ++ni) {
                kb[kc][ni] = *(const bf16x8*)(Kp + (size_t)(kbase + ni * 16 + l15) * DKK
                                              + kc * 32 + quad * 8);
                vb[kc][ni] = *(const bf16x8*)(Vp + (size_t)(ni * 16 + l15) * SEQ
                                              + kbase + kc * 32 + quad * 8);
            }

        #pragma unroll
        for (int mi = 0; mi < 4; ++mi) {
            unsigned long long mw[4];
            #pragma unroll
            for (int r = 0; r < 4; ++r)
                mw[r] = Mrow[(size_t)(mi * 16 + r) * (SEQ / 64) + kt] >> l15;

            f32x4 s[4];
            #pragma unroll
            for (int ni = 0; ni < 4; ++ni) s[ni] = f32x4{0.f, 0.f, 0.f, 0.f};
            #pragma unroll
            for (int kc = 0; kc < 2; ++kc)
                #pragma unroll
                for (int ni = 0; ni < 4; ++ni)
                    s[ni] = __builtin_amdgcn_mfma_f32_16x16x32_bf16(
                        qf[mi][kc], kb[kc][ni], s[ni], 0, 0, 0);

            // P -> LDS in permuted k-order: one b64 per row (4 bf16, ni=0..3)
            #pragma unroll
            for (int r = 0; r < 4; ++r) {
                float p0, p1, p2, p3;
                {
                    float e0 = exp2f(s[0][r] * C), e1 = exp2f(s[1][r] * C);
                    float e2 = exp2f(s[2][r] * C), e3 = exp2f(s[3][r] * C);
                    p0 = (mw[r] >> 0)  & 1 ? e0 : 1.0f;
                    p1 = (mw[r] >> 16) & 1 ? e1 : 1.0f;
                    p2 = (mw[r] >> 32) & 1 ? e2 : 1.0f;
                    p3 = (mw[r] >> 48) & 1 ? e3 : 1.0f;
                }
                *(uint2*)&Ps[wid][(mi * 16 + quad * 4 + r) * 72 + l15 * 4] =
                    make_uint2(pack_bf16x2(p0, p1), pack_bf16x2(p2, p3));
            }

            #pragma unroll
            for (int kc = 0; kc < 2; ++kc) {
                bf16x8 pa = *(const bf16x8*)&Ps[wid][(mi * 16 + l15) * 72 + kc * 32 + quad * 8];
                l_acc[mi] = __builtin_amdgcn_mfma_f32_16x16x32_bf16(
                    pa, onesf, l_acc[mi], 0, 0, 0);
                #pragma unroll
                for (int nd = 0; nd < 4; ++nd)
                    o_acc[mi][nd] = __builtin_amdgcn_mfma_f32_16x16x32_bf16(
                        pa, vb[kc][nd], o_acc[mi][nd], 0, 0, 0);
            }
        }
    }

    // ---- merge 4 per-wave partial (O, l) by plain summation ----
    if (l15 == 0) {
        #pragma unroll
        for (int mi = 0; mi < 4; ++mi)
            #pragma unroll
            for (int r = 0; r < 4; ++r)
                lbuf[wid][mi * 16 + quad * 4 + r] = l_acc[mi][r];
    }
    __syncthreads();

    if (wid == 0) {
        #pragma unroll
        for (int mi = 0; mi < 4; ++mi)
            #pragma unroll
            for (int nd = 0; nd < 4; ++nd)
                #pragma unroll
                for (int r = 0; r < 4; ++r)
                    obuf[(mi * 16 + quad * 4 + r) * 66 + nd * 16 + l15] = o_acc[mi][nd][r];
    }
    __syncthreads();
    if (wid == 1) {
        #pragma unroll
        for (int mi = 0; mi < 4; ++mi)
            #pragma unroll
            for (int nd = 0; nd < 4; ++nd)
                #pragma unroll
                for (int r = 0; r < 4; ++r)
                    obuf[(mi * 16 + quad * 4 + r) * 66 + nd * 16 + l15] += o_acc[mi][nd][r];
    }
    __syncthreads();
    if (wid == 2) {
        #pragma unroll
        for (int mi = 0; mi < 4; ++mi)
            #pragma unroll
            for (int nd = 0; nd < 4; ++nd)
                #pragma unroll
                for (int r = 0; r < 4; ++r)
                    obuf[(mi * 16 + quad * 4 + r) * 66 + nd * 16 + l15] += o_acc[mi][nd][r];
    }
    __syncthreads();
    if (wid == 3) {
        #pragma unroll
        for (int mi = 0; mi < 4; ++mi) {
            #pragma unroll
            for (int r = 0; r < 4; ++r) {
                int row = mi * 16 + quad * 4 + r;
                float L = lbuf[0][row] + lbuf[1][row] + lbuf[2][row] + lbuf[3][row];
                float rinv = 1.0f / L;
                #pragma unroll
                for (int nd = 0; nd < 4; ++nd) {
                    float tot = obuf[row * 66 + nd * 16 + l15] + o_acc[mi][nd][r];
                    Om[((size_t)b * SEQ + q0 + row) * HID + h * DKK + nd * 16 + l15] =
                        f32_bf16(tot * rinv);
                }
            }
        }
    }
}

// ---------------------------------------------------------------------------
// Kernel 3: out = Om @ Wo^T + bo (fp32 out), m97-structure like proj.
// ---------------------------------------------------------------------------
__global__ __launch_bounds__(256, 2)
void outproj_kernel(const unsigned short* __restrict__ Om, const unsigned short* __restrict__ Wob,
                    const float* __restrict__ bo_, float* __restrict__ out)
{
    const int m0 = blockIdx.x * 128;
    const int n0 = blockIdx.y * 128;
    const int tid  = threadIdx.x;
    const int lane = tid & 63, wid = tid >> 6;
    const int wm = (wid >> 1) * 64, wn = (wid & 1) * 64;
    const int l15 = lane & 15, quad = lane >> 4;

    __shared__ __align__(16) unsigned short As[128 * 32];
    __shared__ __align__(16) unsigned short Bs[128 * 32];

    const int r0 = tid >> 2, cg = tid & 3;
    const unsigned short* gA = Om + (size_t)(m0 + r0) * HID + ((cg ^ (r0 & 3)) * 8);
    const unsigned short* gB = Wob + (size_t)(n0 + r0) * HID + ((cg ^ (r0 & 3)) * 8);
    unsigned short* lA0 = &As[tid * 8];
    unsigned short* lA1 = &As[(tid + 256) * 8];
    unsigned short* lB0 = &Bs[tid * 8];
    unsigned short* lB1 = &Bs[(tid + 256) * 8];
    const int cgsel = (quad ^ (l15 & 3)) * 8;

    f32x4 acc[4][4];
    #pragma unroll
    for (int i = 0; i < 4; ++i)
        #pragma unroll
        for (int j = 0; j < 4; ++j)
            acc[i][j] = f32x4{0.f, 0.f, 0.f, 0.f};

    for (int k0 = 0; k0 < HID; k0 += 32) {
        glds16(gA + k0, lA0);
        glds16(gA + (size_t)64 * HID + k0, lA1);
        glds16(gB + k0, lB0);
        glds16(gB + (size_t)64 * HID + k0, lB1);
        __syncthreads();

        bf16x8 af[4], bfr[4];
        #pragma unroll
        for (int mi = 0; mi < 4; ++mi)
            af[mi] = *(const bf16x8*)&As[(wm + mi * 16 + l15) * 32 + cgsel];
        #pragma unroll
        for (int ni = 0; ni < 4; ++ni)
            bfr[ni] = *(const bf16x8*)&Bs[(wn + ni * 16 + l15) * 32 + cgsel];
        #pragma unroll
        for (int mi = 0; mi < 4; ++mi)
            #pragma unroll
            for (int ni = 0; ni < 4; ++ni)
                acc[mi][ni] = __builtin_amdgcn_mfma_f32_16x16x32_bf16(
                    af[mi], bfr[ni], acc[mi][ni], 0, 0, 0);
        __syncthreads();
    }

    #pragma unroll
    for (int mi = 0; mi < 4; ++mi) {
        #pragma unroll
        for (int ni = 0; ni < 4; ++ni) {
            int n = n0 + wn + ni * 16 + l15;
            float bv = bo_[n];
            #pragma unroll
            for (int r = 0; r < 4; ++r) {
                int m = m0 + wm + mi * 16 + quad * 4 + r;
                out[(size_t)m * HID + n] = acc[mi][ni][r] + bv;
            }
        }
    }
}

// ---------------------------------------------------------------------------
extern "C" void kernel_launch(void* const* d_in, const int* in_sizes, int n_in,
                              void* d_out, int out_size, void* d_ws, size_t ws_size,
                              hipStream_t stream) {
    const float* q    = (const float*)d_in[0];
    const float* k    = (const float*)d_in[1];
    const float* v    = (const float*)d_in[2];
    const int*   mask = (const int*)  d_in[3];
    const float* Wq   = (const float*)d_in[4];
    const float* bq   = (const float*)d_in[5];
    const float* Wk   = (const float*)d_in[6];
    const float* bk   = (const float*)d_in[7];
    const float* Wv   = (const float*)d_in[8];
    const float* bv   = (const float*)d_in[9];
    const float* Wo   = (const float*)d_in[10];
    const float* bo   = (const float*)d_in[11];
    float* out = (float*)d_out;

    // workspace layout (bf16 element offsets):
    unsigned short* ws  = (unsigned short*)d_ws;
    unsigned short* qb  = ws;                  // 4194304 elems (B*S*H)
    unsigned short* kbx = ws + 4194304;
    unsigned short* vbx = ws + 8388608;
    unsigned short* Wqb = ws + 12582912;       // 1048576 elems each
    unsigned short* Wkb = ws + 13631488;
    unsigned short* Wvb = ws + 14680064;
    unsigned short* Wob = ws + 15728640;
    unsigned short* Qh  = ws + 16777216;
    unsigned short* Kh  = ws + 20971520;
    unsigned short* Vt  = ws + 25165824;
    unsigned short* Om  = ws;                  // alias qb (dead after proj)
    unsigned long long* Mb = (unsigned long long*)(ws + 29360128);  // 1 MB

    const int nPre = 3 * (1 << 20) + 4 * (1 << 18) + (1 << 17);
    prepass_kernel<<<dim3(nPre / 256), 256, 0, stream>>>(
        q, k, v, Wq, Wk, Wv, Wo, mask, qb, kbx, vbx, Wqb, Wkb, Wvb, Wob, Mb);

    proj_kernel<<<dim3(32, 8, 3), 256, 0, stream>>>(qb, kbx, vbx, Wqb, Wkb, Wvb,
                                                    bq, bk, bv, Qh, Kh, Vt);
    attn_kernel<<<dim3(32, NHEAD, 2), 256, 0, stream>>>(Qh, Kh, Vt, Mb, Om);
    outproj_kernel<<<dim3(32, 8, 1), 256, 0, stream>>>(Om, Wob, bo, out);
}